// Round 9
// baseline (103.108 us; speedup 1.0000x reference)
//
#include <hip/hip_runtime.h>
#include <hip/hip_bf16.h>
#include <math.h>

// out[n,:] = s1 .* FWHT( (u/4096) .* FWHT( s2 .* x[n,:] ) ),
// u = g_mu + softplus(g_rho)*epsilon, FWHT = unnormalized Walsh-Hadamard.
//
// R9: radix-64x64. One row per 128-thread (2-wave) block, 32 floats/thread.
// H64 = 5 in-register butterfly levels + 1 cross-lane level (lane l <-> l^1,
// DPP quad_perm 0xB1 on the VALU pipe -- no DS traffic). Only TWO LDS
// transposes per row (vs 4 rotations in radix-16): DS/row 1126 cyc vs 2612.
//
// Ownership: phase A: thread t holds elements [32t, 32t+32) = line h=t>>1,
//   g-half 32*(t&1). phase B (after T1): g = t>>1, h-half 32*(t&1).
// LDS map: addr(h,g) = h*64 + (g ^ ((h&7)<<2)).
//   b32 side (T1-read/T2-write, h varies): bank = (lane>>1)^const -> 2
//   lanes/bank = free (m136). b128 side (T1-write/T2-read): 8 lanes per
//   4-bank group = 8 words/bank = the 1KB/instr bandwidth minimum.
// Hazards: T1-read set of thread t == T2-write set of thread t (same
//   formula) -> same-thread DS-FIFO ordering suffices; the only cross-thread
//   edges are T1 write->read and T2 write->read -> exactly 2 __syncthreads.

#define WHVI_D 4096

__global__ __launch_bounds__(256)
void u_precompute_kernel(const float* __restrict__ g_mu,
                         const float* __restrict__ g_rho,
                         const float* __restrict__ g_eps,
                         float* __restrict__ u_perm) {
    int k = blockIdx.x * 256 + threadIdx.x;  // 0..4095, coalesced reads
    float rho = g_rho[k];
    float sp = fmaxf(rho, 0.0f) + __logf(1.0f + __expf(-fabsf(rho)));
    float uu = (g_mu[k] + sp * g_eps[k]) * (1.0f / 4096.0f);
    // element i = h*64+g is held (phase B) by thread t = 2g + (h>>5), reg
    // r = h&31  ->  store at u_perm[t*32 + r] (per-thread contiguous b128)
    int h = k >> 6, g = k & 63;
    u_perm[(2 * g + (h >> 5)) * 32 + (h & 31)] = uu;
}

__device__ __forceinline__ float dpp_xor1(float x) {
    int i = __builtin_bit_cast(int, x);
    // quad_perm [1,0,3,2] = 0xB1 : lane <-> lane^1
    int p = __builtin_amdgcn_mov_dpp(i, 0xB1, 0xF, 0xF, 0);
    return __builtin_bit_cast(float, p);
}

// cross-lane butterfly between the two 32-halves (partner thread t^1):
// lower' = lower + upper ; upper' = lower - upper  ->  v = sgn*v + partner
__device__ __forceinline__ void bfly_cross(float v[32], float sgn) {
#pragma unroll
    for (int k = 0; k < 32; ++k) {
        float p = dpp_xor1(v[k]);
        v[k] = fmaf(sgn, v[k], p);
    }
}

__device__ __forceinline__ void fwht32(float v[32]) {
#pragma unroll
    for (int s = 1; s < 32; s <<= 1) {
#pragma unroll
        for (int i = 0; i < 32; ++i) {
            if ((i & s) == 0) {
                float a = v[i], b = v[i | s];
                v[i] = a + b;
                v[i | s] = a - b;
            }
        }
    }
}

__global__ __launch_bounds__(128)
void whvi64x2_kernel(const float* __restrict__ x,
                     const float* __restrict__ s1,
                     const float* __restrict__ s2,
                     const float* __restrict__ u_perm,
                     float* __restrict__ out,
                     int nrows) {
    __shared__ __align__(16) float lds[WHVI_D];  // 16 KB

    const int t = threadIdx.x;      // 0..127
    const int half = t & 1;         // which 32-half of the 64-line
    const int hl = t >> 1;          // line index 0..63
    const float sgn = half ? -1.0f : 1.0f;
    const int row = blockIdx.x;
    if (row >= nrows) return;
    const size_t base = (size_t)row * WHVI_D + t * 32;

    float v[32];

    // ---- load x[row, 32t..32t+32) and s2, scale (8x b128 each) ----
    {
        const float4* xv = reinterpret_cast<const float4*>(x + base);
        const float4* sv = reinterpret_cast<const float4*>(s2 + t * 32);
#pragma unroll
        for (int c = 0; c < 8; ++c) {
            float4 a = xv[c], s = sv[c];
            v[4 * c + 0] = a.x * s.x;
            v[4 * c + 1] = a.y * s.y;
            v[4 * c + 2] = a.z * s.z;
            v[4 * c + 3] = a.w * s.w;
        }
    }

    // ---- FWHT#1, g-part: H64 on g (cross level + 5 reg levels) ----
    bfly_cross(v, sgn);
    fwht32(v);

    // ---- T1: write (h=hl, g=32*half+4c+j) b128; bar; read (h=32*half+r, g=hl) b32 ----
#pragma unroll
    for (int c = 0; c < 8; ++c) {
        int a0 = hl * 64 + ((half * 32 + 4 * c) ^ ((hl & 7) << 2));
        *reinterpret_cast<float4*>(&lds[a0]) =
            make_float4(v[4 * c + 0], v[4 * c + 1], v[4 * c + 2], v[4 * c + 3]);
    }
    __syncthreads();
#pragma unroll
    for (int r = 0; r < 32; ++r)
        v[r] = lds[(half * 32 + r) * 64 + (hl ^ ((r & 7) << 2))];

    // ---- FWHT#1, h-part: H64 on h -> FWHT#1 done ----
    bfly_cross(v, sgn);
    fwht32(v);

    // ---- diagonal u (1/4096 folded): u_perm[t*32+r] matches ownership ----
    {
        const float4* uv = reinterpret_cast<const float4*>(u_perm + t * 32);
#pragma unroll
        for (int c = 0; c < 8; ++c) {
            float4 uu = uv[c];
            v[4 * c + 0] *= uu.x;
            v[4 * c + 1] *= uu.y;
            v[4 * c + 2] *= uu.z;
            v[4 * c + 3] *= uu.w;
        }
    }

    // ---- FWHT#2, h-part (h still in regs) ----
    bfly_cross(v, sgn);
    fwht32(v);

    // ---- T2: write (h=32*half+r, g=hl) b32 (same addrs as T1-read ->
    //      same-thread FIFO, no barrier); bar; read (h=hl, g=32*half+..) b128 ----
#pragma unroll
    for (int r = 0; r < 32; ++r)
        lds[(half * 32 + r) * 64 + (hl ^ ((r & 7) << 2))] = v[r];
    __syncthreads();
#pragma unroll
    for (int c = 0; c < 8; ++c) {
        int a0 = hl * 64 + ((half * 32 + 4 * c) ^ ((hl & 7) << 2));
        float4 tt = *reinterpret_cast<const float4*>(&lds[a0]);
        v[4 * c + 0] = tt.x;
        v[4 * c + 1] = tt.y;
        v[4 * c + 2] = tt.z;
        v[4 * c + 3] = tt.w;
    }

    // ---- FWHT#2, g-part -> natural order: thread holds [32t, 32t+32) ----
    bfly_cross(v, sgn);
    fwht32(v);

    // ---- s1 scale + store (8x b128) ----
    {
        const float4* sv = reinterpret_cast<const float4*>(s1 + t * 32);
        float4* ov = reinterpret_cast<float4*>(out + base);
#pragma unroll
        for (int c = 0; c < 8; ++c) {
            float4 s = sv[c];
            ov[c] = make_float4(v[4 * c + 0] * s.x, v[4 * c + 1] * s.y,
                                v[4 * c + 2] * s.z, v[4 * c + 3] * s.w);
        }
    }
}

extern "C" void kernel_launch(void* const* d_in, const int* in_sizes, int n_in,
                              void* d_out, int out_size, void* d_ws, size_t ws_size,
                              hipStream_t stream) {
    const float* x     = (const float*)d_in[0];
    const float* s1    = (const float*)d_in[1];
    const float* s2    = (const float*)d_in[2];
    const float* g_mu  = (const float*)d_in[3];
    const float* g_rho = (const float*)d_in[4];
    const float* g_eps = (const float*)d_in[5];
    // d_in[6] is H — unused; the FWHT realizes it exactly.
    float* out = (float*)d_out;

    const int nrows = in_sizes[0] / WHVI_D;  // 8192

    float* u_perm = (float*)d_ws;  // 16 KB of workspace
    u_precompute_kernel<<<WHVI_D / 256, 256, 0, stream>>>(g_mu, g_rho, g_eps, u_perm);

    whvi64x2_kernel<<<nrows, 128, 0, stream>>>(x, s1, s2, u_perm, out, nrows);
}

// Round 10
// 63.658 us; speedup vs baseline: 1.6197x; 1.6197x over previous
//
#include <hip/hip_runtime.h>
#include <hip/hip_bf16.h>
#include <math.h>

// out[n,:] = s1 .* FWHT( (u/4096) .* FWHT( s2 .* x[n,:] ) ),
// u = g_mu + softplus(g_rho)*epsilon, FWHT = unnormalized Walsh-Hadamard.
//
// R10: f2 row-pair (two rows in the two halves of each VGPR pair, all
// butterflies v_pk_add_f32) x radix-64x64 (TWO LDS transposes instead of
// four radix-16 rotations). H64 = 4 in-register levels + 2 quad-DPP levels:
//   digit bit4 <-> lane^1 (quad_perm 0xB1, proven in R9)
//   digit bit5 <-> lane^2 (quad_perm 0x4E)
// Ownership: thread t = (h = t>>2, quarter q = t&3) holds v[j] = element
// (h, g = 16q + j)  ==  flat index i = 16t + j  (so all global I/O keeps the
// verified b128 16t+j pattern).
// LDS map (f2 units): A(h,g) = h*64 + (g ^ (2*(h&7))).
//   T1-write b128 (g-contiguous pairs): 8 words/bank  = minimum.
//   T1-read  b64  (h varies, g fixed):  4 words/bank  = minimum.
//   Both maps bijective -> T1-read / T2-write are same-thread same-addr
//   (DS FIFO ordered); only 2 __syncthreads per pair.
// 16 f2 data regs/thread (R9's failure was 32 + starved allocator).

#define WHVI_D 4096

typedef float f2 __attribute__((ext_vector_type(2)));

__global__ __launch_bounds__(256)
void u_precompute_kernel(const float* __restrict__ g_mu,
                         const float* __restrict__ g_rho,
                         const float* __restrict__ g_eps,
                         float* __restrict__ u_perm) {
    int k = blockIdx.x * 256 + threadIdx.x;  // 0..4095, coalesced
    float rho = g_rho[k];
    float sp = fmaxf(rho, 0.0f) + __logf(1.0f + __expf(-fabsf(rho)));
    float uu = (g_mu[k] + sp * g_eps[k]) * (1.0f / 4096.0f);
    // At diag time thread t holds element (h = 16*(t&3) + r, g = t>>2),
    // i.e. i = 64h + g. Invert: store u[i] at u_perm[(4g + q)*16 + r].
    int h = k >> 6, g = k & 63;
    int q = (h >> 4) & 3, r = h & 15;
    u_perm[(4 * g + q) * 16 + r] = uu;
}

template <int CTRL>
__device__ __forceinline__ float dppf(float x) {
    return __builtin_bit_cast(float,
        __builtin_amdgcn_mov_dpp(__builtin_bit_cast(int, x), CTRL, 0xF, 0xF, false));
}

// one cross-lane butterfly level: v' = sgn*v + partner  (R9-verified form)
template <int CTRL>
__device__ __forceinline__ void dpp_level(f2 v[16], float sgn) {
#pragma unroll
    for (int k = 0; k < 16; ++k) {
        float px = dppf<CTRL>(v[k].x);
        float py = dppf<CTRL>(v[k].y);
        v[k].x = fmaf(sgn, v[k].x, px);
        v[k].y = fmaf(sgn, v[k].y, py);
    }
}

// H64 over one 6-bit digit: bits 0-3 in regs (pk), bit4 = lane^1, bit5 = lane^2.
__device__ __forceinline__ void h64(f2 v[16], float sA, float sB) {
#pragma unroll
    for (int s = 1; s < 16; s <<= 1) {
#pragma unroll
        for (int i = 0; i < 16; ++i) {
            if ((i & s) == 0) {
                f2 a = v[i], b = v[i | s];
                v[i] = a + b;       // v_pk_add_f32
                v[i | s] = a - b;
            }
        }
    }
    dpp_level<0xB1>(v, sA);  // quad_perm [1,0,3,2] : lane^1
    dpp_level<0x4E>(v, sB);  // quad_perm [2,3,0,1] : lane^2
}

__device__ __forceinline__ int Ahg(int h, int g) {
    return h * 64 + (g ^ ((h & 7) << 1));
}

__global__ __launch_bounds__(256)
void whvi64p_kernel(const float* __restrict__ x,
                    const float* __restrict__ s1,
                    const float* __restrict__ s2,
                    const float* __restrict__ u_perm,
                    float* __restrict__ out,
                    int nrows) {
    __shared__ __align__(16) f2 lds[WHVI_D];  // 32 KB

    const int t = threadIdx.x;     // 0..255
    const int q = t & 3;           // quarter (lane bits 0-1)
    const int h = t >> 2;          // owned h-line (phase A) / g-line (phase B)
    const float sA = (t & 1) ? -1.0f : 1.0f;   // digit bit4 sign
    const float sB = (t & 2) ? -1.0f : 1.0f;   // digit bit5 sign

    const int r0 = blockIdx.x * 2;
    const bool r1_valid = (r0 + 1 < nrows);
    const size_t base0 = (size_t)r0 * WHVI_D;
    const size_t base1 = (size_t)(r0 + (r1_valid ? 1 : 0)) * WHVI_D;

    f2 v[16];

    // ---- load row pair + s2, pack (b128, i = 16t + j) ----
    {
        const float4* xa = reinterpret_cast<const float4*>(x + base0 + t * 16);
        const float4* xb = reinterpret_cast<const float4*>(x + base1 + t * 16);
        const float4* sv = reinterpret_cast<const float4*>(s2 + t * 16);
#pragma unroll
        for (int c = 0; c < 4; ++c) {
            float4 a = xa[c], b = xb[c], s = sv[c];
            v[4 * c + 0] = f2{a.x * s.x, b.x * s.x};
            v[4 * c + 1] = f2{a.y * s.y, b.y * s.y};
            v[4 * c + 2] = f2{a.z * s.z, b.z * s.z};
            v[4 * c + 3] = f2{a.w * s.w, b.w * s.w};
        }
    }

    // ---- FWHT#1 g-side: H64 over g (regs j = g bits 0-3; q = bits 4-5) ----
    h64(v, sA, sB);

    // issue u_perm loads early (first use ~2 h64's later)
    const float4* upv = reinterpret_cast<const float4*>(u_perm + t * 16);
    float4 upr[4];
#pragma unroll
    for (int c = 0; c < 4; ++c) upr[c] = upv[c];

    // ---- T1: write (h, g=16q+2c..) b128; bar; read (h'=16q+r, g'=t>>2) b64 ----
#pragma unroll
    for (int c = 0; c < 8; ++c) {
        int a0 = Ahg(h, 16 * q + 2 * c);
        *reinterpret_cast<float4*>(&lds[a0]) =
            make_float4(v[2 * c].x, v[2 * c].y, v[2 * c + 1].x, v[2 * c + 1].y);
    }
    __syncthreads();
#pragma unroll
    for (int r = 0; r < 16; ++r)
        v[r] = lds[Ahg(16 * q + r, h)];   // note: h now plays the g-own role

    // ---- FWHT#1 h-side: H64 over h ----
    h64(v, sA, sB);

    // ---- diagonal u (1/4096 folded), per-thread-contiguous b128 ----
#pragma unroll
    for (int c = 0; c < 4; ++c) {
        v[4 * c + 0] *= upr[c].x;
        v[4 * c + 1] *= upr[c].y;
        v[4 * c + 2] *= upr[c].z;
        v[4 * c + 3] *= upr[c].w;
    }

    // ---- FWHT#2 h-side (h digits still in regs/lanes) ----
    h64(v, sA, sB);

    // issue s1 loads (first use after T2 + h64)
    const float4* s1v = reinterpret_cast<const float4*>(s1 + t * 16);
    float4 s1r[4];
#pragma unroll
    for (int c = 0; c < 4; ++c) s1r[c] = s1v[c];

    // ---- T2: write back same addrs as T1-read (same-thread, FIFO-safe);
    //      bar; read b128 rows (= T1-write addrs) ----
#pragma unroll
    for (int r = 0; r < 16; ++r)
        lds[Ahg(16 * q + r, h)] = v[r];
    __syncthreads();
#pragma unroll
    for (int c = 0; c < 8; ++c) {
        int a0 = Ahg(h, 16 * q + 2 * c);
        float4 tt = *reinterpret_cast<const float4*>(&lds[a0]);
        v[2 * c]     = f2{tt.x, tt.y};
        v[2 * c + 1] = f2{tt.z, tt.w};
    }

    // ---- FWHT#2 g-side -> natural order: v[j] = out-element 16t + j ----
    h64(v, sA, sB);

    // ---- s1 scale + store both rows (b128) ----
    {
        float4* o0 = reinterpret_cast<float4*>(out + base0 + t * 16);
        float4* o1 = reinterpret_cast<float4*>(out + base1 + t * 16);
#pragma unroll
        for (int c = 0; c < 4; ++c) {
            float4 s = s1r[c];
            o0[c] = make_float4(v[4 * c + 0].x * s.x, v[4 * c + 1].x * s.y,
                                v[4 * c + 2].x * s.z, v[4 * c + 3].x * s.w);
            if (r1_valid)
                o1[c] = make_float4(v[4 * c + 0].y * s.x, v[4 * c + 1].y * s.y,
                                    v[4 * c + 2].y * s.z, v[4 * c + 3].y * s.w);
        }
    }
}

extern "C" void kernel_launch(void* const* d_in, const int* in_sizes, int n_in,
                              void* d_out, int out_size, void* d_ws, size_t ws_size,
                              hipStream_t stream) {
    const float* x     = (const float*)d_in[0];
    const float* s1    = (const float*)d_in[1];
    const float* s2    = (const float*)d_in[2];
    const float* g_mu  = (const float*)d_in[3];
    const float* g_rho = (const float*)d_in[4];
    const float* g_eps = (const float*)d_in[5];
    // d_in[6] is H — unused; the FWHT realizes it exactly.
    float* out = (float*)d_out;

    const int nrows = in_sizes[0] / WHVI_D;  // 8192

    float* u_perm = (float*)d_ws;  // 16 KB of workspace
    u_precompute_kernel<<<WHVI_D / 256, 256, 0, stream>>>(g_mu, g_rho, g_eps, u_perm);

    const int npairs = (nrows + 1) / 2;
    whvi64p_kernel<<<npairs, 256, 0, stream>>>(x, s1, s2, u_perm, out, nrows);
}